// Round 3
// baseline (1270.219 us; speedup 1.0000x reference)
//
#include <hip/hip_runtime.h>
#include <math.h>

#define CC 32
#define CHUNK 4096  // 256 threads * 16 elems, for the rptr scan

static inline int cdiv(long long a, int b) { return (int)((a + b - 1) / b); }

// ---------- degree (by src, float) + CSR count (by dst, int) in one pass ----------
__global__ void k_degcnt(const int* __restrict__ src, const int* __restrict__ dst,
                         float* __restrict__ deg, int* __restrict__ cnt, int E) {
  int e = blockIdx.x * blockDim.x + threadIdx.x;
  if (e < E) {
    atomicAdd(&deg[src[e]], 1.0f);
    atomicAdd(&cnt[dst[e]], 1);
  }
}

__global__ void k_dis(float* __restrict__ dis, int N) {
  int i = blockIdx.x * blockDim.x + threadIdx.x;
  if (i < N) {
    float d = dis[i];
    dis[i] = (d > 0.f) ? rsqrtf(fmaxf(d, 1.f)) : 0.f;
  }
}

// ---------- CSR build: chunk sums -> serial chunk scan -> per-chunk fill ----------
__global__ void k_chunksum(const int* __restrict__ cnt, int* __restrict__ csum, int N) {
  int base = blockIdx.x * CHUNK;
  int v = 0;
  for (int i = threadIdx.x; i < CHUNK; i += 256) {
    int idx = base + i;
    if (idx < N) v += cnt[idx];
  }
  for (int m = 32; m; m >>= 1) v += __shfl_xor(v, m);
  __shared__ int ws[4];
  if ((threadIdx.x & 63) == 0) ws[threadIdx.x >> 6] = v;
  __syncthreads();
  if (threadIdx.x == 0) csum[blockIdx.x] = ws[0] + ws[1] + ws[2] + ws[3];
}

__global__ void k_scancsum(int* __restrict__ csum, int nb, int* __restrict__ rptr,
                           int N, int tot) {
  int acc = 0;
  for (int i = 0; i < nb; ++i) { int v = csum[i]; csum[i] = acc; acc += v; }
  rptr[N] = tot;
}

// exclusive scan within chunk; writes rptr[i] and cursor (in-place over cnt)
__global__ void k_fillrptr(int* __restrict__ cnt, const int* __restrict__ csum,
                           int* __restrict__ rptr, int N) {
  int base = blockIdx.x * CHUNK + threadIdx.x * 16;
  int v[16];
  int tot = 0;
#pragma unroll
  for (int q = 0; q < 16; ++q) {
    int idx = base + q;
    v[q] = (idx < N) ? cnt[idx] : 0;
    tot += v[q];
  }
  __shared__ int sh[256];
  sh[threadIdx.x] = tot;
  __syncthreads();
  for (int off = 1; off < 256; off <<= 1) {
    int add = (threadIdx.x >= off) ? sh[threadIdx.x - off] : 0;
    __syncthreads();
    sh[threadIdx.x] += add;
    __syncthreads();
  }
  int excl = sh[threadIdx.x] - tot + csum[blockIdx.x];
#pragma unroll
  for (int q = 0; q < 16; ++q) {
    int idx = base + q;
    if (idx < N) { rptr[idx] = excl; cnt[idx] = excl; }
    excl += v[q];
  }
}

// fill E real edges with w = -dis*dis (self-loops handled in-register by GAT)
__global__ void k_fill(const int* __restrict__ src, const int* __restrict__ dst,
                       const float* __restrict__ dis, int* __restrict__ cursor,
                       int* __restrict__ gsrc, float* __restrict__ gw, int E) {
  int e = blockIdx.x * blockDim.x + threadIdx.x;
  if (e >= E) return;
  int s = src[e], d = dst[e];
  int p = atomicAdd(&cursor[d], 1);
  gsrc[p] = s;
  gw[p] = -dis[s] * dis[d];
}

// ---------- fused Cheb step: slot-parallel gather + recurrence + out += Tx@W ----
// one 64-lane wave per node; lane = slot(8) x cq(8); float4 per lane = 4 channels
__global__ void k_cheb2(const float* __restrict__ x_in, const float* __restrict__ x_sub,
                        const int* __restrict__ rptr, const int* __restrict__ gsrc,
                        const float* __restrict__ gw, const float* __restrict__ W,
                        float scale, float* __restrict__ tx_out, float* __restrict__ out,
                        int N) {
  __shared__ float wl[1024];
  for (int i = threadIdx.x; i < 1024; i += 256) wl[i] = W[i];
  __syncthreads();
  int node = blockIdx.x * 4 + (threadIdx.x >> 6);
  int lane = threadIdx.x & 63;
  if (node >= N) return;
  int slot = lane >> 3, cq = lane & 7;
  int beg = rptr[node], end = rptr[node + 1];
  float tx = 0.f, ty = 0.f, tz = 0.f, tw = 0.f;
  for (int base = beg; base < end; base += 64) {
    int rem = end - base;
    int sj = 0; float wj = 0.f;
    if (lane < rem) { sj = gsrc[base + lane]; wj = gw[base + lane]; }
    int remc = rem < 64 ? rem : 64;
    int nit = (remc + 7) >> 3;
    for (int it = 0; it < nit; ++it) {
      int idx = it * 8 + slot;
      int s = __shfl(sj, idx, 64);
      float wv = __shfl(wj, idx, 64);  // 0 for idx >= remc -> no contribution
      float4 j4 = *(const float4*)(x_in + (long long)s * 32 + cq * 4);
      tx += wv * j4.x; ty += wv * j4.y; tz += wv * j4.z; tw += wv * j4.w;
    }
  }
#pragma unroll
  for (int m = 8; m <= 32; m <<= 1) {
    tx += __shfl_xor(tx, m, 64);
    ty += __shfl_xor(ty, m, 64);
    tz += __shfl_xor(tz, m, 64);
    tw += __shfl_xor(tw, m, 64);
  }
  long long o = (long long)node * 32 + cq * 4;
  float ta[4] = {scale * tx, scale * ty, scale * tz, scale * tw};
  if (x_sub) {
    float4 s4 = *(const float4*)(x_sub + o);
    ta[0] -= s4.x; ta[1] -= s4.y; ta[2] -= s4.z; ta[3] -= s4.w;
  }
  if (tx_out && slot == 0) {
    float4 t4 = {ta[0], ta[1], ta[2], ta[3]};
    *(float4*)(tx_out + o) = t4;
  }
  float ax = 0.f, ay = 0.f, az = 0.f, aw = 0.f;
#pragma unroll
  for (int c = 0; c < 32; ++c) {
    float bc = __shfl(ta[c & 3], c >> 2, 64);
    const float4 w4 = *(const float4*)&wl[c * 32 + cq * 4];
    ax += bc * w4.x; ay += bc * w4.y; az += bc * w4.z; aw += bc * w4.w;
  }
  if (slot == 0) {
    float4 cur = *(float4*)(out + o);
    cur.x += ax; cur.y += ay; cur.z += az; cur.w += aw;
    *(float4*)(out + o) = cur;
  }
}

// out[row][col] = T[row][:] @ W[32][32] + bias[col]   (k=0 term, init)
__global__ void k_gemm32b(const float* __restrict__ T, const float* __restrict__ W,
                          const float* __restrict__ bias, float* __restrict__ out,
                          int N) {
  __shared__ float w[1024];
  for (int i = threadIdx.x; i < 1024; i += 256) w[i] = W[i];
  __syncthreads();
  int row = blockIdx.x * 8 + (threadIdx.x >> 5);
  int col = threadIdx.x & 31;
  if (row >= N) return;
  const float* tr = T + (long long)row * 32;
  float acc = 0.f;
#pragma unroll
  for (int c = 0; c < 32; ++c) acc += tr[c] * w[c * 32 + col];
  out[(long long)row * 32 + col] = acc + bias[col];
}

// h = x @ lin_w (N x 64), plus per-node attention scalars bl = h.att_l, br = h.att_r
// one 64-lane wave per row; col = hd*32 + ch
__global__ void k_gemmh(const float* __restrict__ T, const float* __restrict__ W,
                        const float* __restrict__ attl, const float* __restrict__ attr,
                        float* __restrict__ h, float* __restrict__ bl,
                        float* __restrict__ br, int N) {
  __shared__ float w[2048];
  for (int i = threadIdx.x; i < 2048; i += 256) w[i] = W[i];
  __syncthreads();
  int row = blockIdx.x * 4 + (threadIdx.x >> 6);
  int col = threadIdx.x & 63;
  if (row >= N) return;
  const float* tr = T + (long long)row * 32;
  float acc = 0.f;
#pragma unroll
  for (int c = 0; c < 32; ++c) acc += tr[c] * w[c * 64 + col];
  h[(long long)row * 64 + col] = acc;
  float pl = acc * attl[col], pr = acc * attr[col];
#pragma unroll
  for (int m = 16; m; m >>= 1) {
    pl += __shfl_xor(pl, m, 64);
    pr += __shfl_xor(pr, m, 64);
  }
  if ((col & 31) == 0) {
    bl[row * 2 + (col >> 5)] = pl;
    br[row * 2 + (col >> 5)] = pr;
  }
}

// ---------- fused SuperGAT: slot-parallel gather, no-max softmax, in-register
// self-loop, bias + head-mean + leaky+residual + BN partials.
// one 64-lane wave per node; lane = slot(4) x head(2) x cq(8)
__global__ void k_expgat2(const float* __restrict__ h, const int* __restrict__ rptr,
                          const int* __restrict__ gsrc, const float* __restrict__ bl,
                          const float* __restrict__ br, const float* __restrict__ gb,
                          float* __restrict__ y, float* __restrict__ bns, int N) {
  __shared__ float ls[64];
  for (int i = threadIdx.x; i < 64; i += 256) ls[i] = 0.f;
  __syncthreads();
  int node = blockIdx.x * 4 + (threadIdx.x >> 6);
  int lane = threadIdx.x & 63;
  int slot = lane >> 4, hd = (lane >> 3) & 1, cq = lane & 7;
  if (node < N) {
    float4 i4 = *(const float4*)(h + (long long)node * 64 + hd * 32 + cq * 4);
    float brh = br[node * 2 + hd];
    float2 bln = *(const float2*)(bl + node * 2);
    // self-loop contribution (no gather; j == i)
    float lgs = i4.x * i4.x + i4.y * i4.y + i4.z * i4.z + i4.w * i4.w;
    lgs += __shfl_xor(lgs, 1, 64);
    lgs += __shfl_xor(lgs, 2, 64);
    lgs += __shfl_xor(lgs, 4, 64);
    float lin = (hd ? bln.y : bln.x) + brh;
    float sg = 1.f / (1.f + __expf(-lgs));
    float a = lin * sg;
    a = (a > 0.f) ? a : 0.2f * a;
    float es = __expf(a);
    float s_acc = 0.f;
    float vx = 0.f, vy = 0.f, vz = 0.f, vw = 0.f;
    if (slot == 0) {
      s_acc = es;
      vx = es * i4.x; vy = es * i4.y; vz = es * i4.z; vw = es * i4.w;
    }
    int beg = rptr[node], end = rptr[node + 1];
    for (int base = beg; base < end; base += 64) {
      int rem = end - base;
      int sj = 0; float bl0 = 0.f, bl1 = 0.f;
      if (lane < rem) {
        sj = gsrc[base + lane];
        float2 b2 = *(const float2*)(bl + sj * 2);
        bl0 = b2.x; bl1 = b2.y;
      }
      int remc = rem < 64 ? rem : 64;
      int nit = (remc + 3) >> 2;
      for (int it = 0; it < nit; ++it) {
        int idx = it * 4 + slot;
        int s = __shfl(sj, idx, 64);
        float4 j4 = *(const float4*)(h + (long long)s * 64 + hd * 32 + cq * 4);
        float lg = j4.x * i4.x + j4.y * i4.y + j4.z * i4.z + j4.w * i4.w;
        lg += __shfl_xor(lg, 1, 64);
        lg += __shfl_xor(lg, 2, 64);
        lg += __shfl_xor(lg, 4, 64);
        float b0 = __shfl(bl0, idx, 64);
        float b1 = __shfl(bl1, idx, 64);
        float li = (hd ? b1 : b0) + brh;
        float sgm = 1.f / (1.f + __expf(-lg));
        float av = li * sgm;
        av = (av > 0.f) ? av : 0.2f * av;
        float e = (idx < remc) ? __expf(av) : 0.f;
        s_acc += e;
        vx += e * j4.x; vy += e * j4.y; vz += e * j4.z; vw += e * j4.w;
      }
    }
    // reduce across the 4 slots
#pragma unroll
    for (int m = 16; m <= 32; m <<= 1) {
      s_acc += __shfl_xor(s_acc, m, 64);
      vx += __shfl_xor(vx, m, 64);
      vy += __shfl_xor(vy, m, 64);
      vz += __shfl_xor(vz, m, 64);
      vw += __shfl_xor(vw, m, 64);
    }
    float inv = 1.f / s_acc;
    vx *= inv; vy *= inv; vz *= inv; vw *= inv;
    // head mean via xor 8 (flips hd)
    vx = 0.5f * (vx + __shfl_xor(vx, 8, 64));
    vy = 0.5f * (vy + __shfl_xor(vy, 8, 64));
    vz = 0.5f * (vz + __shfl_xor(vz, 8, 64));
    vw = 0.5f * (vw + __shfl_xor(vw, 8, 64));
    float4 g4 = *(const float4*)(gb + cq * 4);
    float x2, yv0, yv1, yv2, yv3;
    x2 = vx + g4.x; yv0 = ((x2 > 0.f) ? x2 : 0.01f * x2) + x2;
    x2 = vy + g4.y; yv1 = ((x2 > 0.f) ? x2 : 0.01f * x2) + x2;
    x2 = vz + g4.z; yv2 = ((x2 > 0.f) ? x2 : 0.01f * x2) + x2;
    x2 = vw + g4.w; yv3 = ((x2 > 0.f) ? x2 : 0.01f * x2) + x2;
    if (slot == 0 && hd == 0) {
      float4 yv = {yv0, yv1, yv2, yv3};
      *(float4*)(y + (long long)node * 32 + cq * 4) = yv;
      atomicAdd(&ls[cq * 4 + 0], yv0);
      atomicAdd(&ls[cq * 4 + 1], yv1);
      atomicAdd(&ls[cq * 4 + 2], yv2);
      atomicAdd(&ls[cq * 4 + 3], yv3);
      atomicAdd(&ls[32 + cq * 4 + 0], yv0 * yv0);
      atomicAdd(&ls[32 + cq * 4 + 1], yv1 * yv1);
      atomicAdd(&ls[32 + cq * 4 + 2], yv2 * yv2);
      atomicAdd(&ls[32 + cq * 4 + 3], yv3 * yv3);
    }
  }
  __syncthreads();
  if (threadIdx.x < 64) atomicAdd(&bns[threadIdx.x], ls[threadIdx.x]);
}

// in-place safe (y may alias out)
__global__ void k_bnfinal(const float* __restrict__ y, const float* __restrict__ bns,
                          const float* __restrict__ g, const float* __restrict__ b,
                          float* __restrict__ out, int N) {
  int i = blockIdx.x * blockDim.x + threadIdx.x;
  if (i >= N * CC) return;
  int c = i & 31;
  float inv_n = 1.f / (float)N;
  float mu = bns[c] * inv_n;
  float var = bns[32 + c] * inv_n - mu * mu;
  out[i] = (y[i] - mu) * rsqrtf(var + 1e-5f) * g[c] + b[c];
}

extern "C" void kernel_launch(void* const* d_in, const int* in_sizes, int n_in,
                              void* d_out, int out_size, void* d_ws, size_t ws_size,
                              hipStream_t stream) {
  const float* patch = (const float*)d_in[0];
  const int* eidx = (const int*)d_in[1];
  // d_in[2] = edge_attr (unused by reference)
  const float* cheb_w = (const float*)d_in[3];
  const float* cheb_b = (const float*)d_in[4];
  const float* lin_w = (const float*)d_in[5];
  const float* att_l = (const float*)d_in[6];
  const float* att_r = (const float*)d_in[7];
  const float* gat_b = (const float*)d_in[8];
  const float* bn_g = (const float*)d_in[9];
  const float* bn_b = (const float*)d_in[10];
  float* out = (float*)d_out;

  const int N = in_sizes[0] / CC;   // 100000
  const int E = in_sizes[1] / 2;    // 1600000
  const int* src = eidx;
  const int* dst = eidx + E;

  // workspace layout (~40 MB); all region starts even-float (8B) aligned
  float* R0 = (float*)d_ws;                  // N*32 (Tx ping; h = R0 as N*64)
  float* R1 = R0 + (size_t)N * 32;           // N*32 (Tx pong)
  float* gw = R1 + (size_t)N * 32;           // E floats (cheb edge weights)
  int* gsrc = (int*)(gw + E);                // E ints (dst-sorted src)
  int* grptr = gsrc + E;                     // N+2 ints (CSR row ptr, padded even)
  int* cnt = grptr + (N + 2);                // N ints (count, then cursor) [zeroed]
  int* csum = cnt + N;                       // 64 ints (chunk sums)       [zeroed]
  float* dis = (float*)(csum + 64);          // N floats                   [zeroed]
  float* bns = dis + N;                      // 64 floats                  [zeroed]
  float* bl = bns + 64;                      // N*2 floats (h . att_l per head)
  float* br = bl + (size_t)N * 2;            // N*2 floats (h . att_r per head)
  float* h = R0;                             // N*64 overlays R0..R1 after cheb

  const int B = 256;
  const long long NC = (long long)N * 32;

  // zero cnt, csum, dis, bns in one shot (contiguous)
  hipMemsetAsync(cnt, 0, sizeof(int) * ((size_t)N * 2 + 128), stream);

  // degree-by-src (sym norm) + count-by-dst (CSR) in one pass
  k_degcnt<<<cdiv(E, B), B, 0, stream>>>(src, dst, dis, cnt, E);
  k_dis<<<cdiv(N, B), B, 0, stream>>>(dis, N);

  // CSR build over E real edges (self-loops handled in-register by GAT)
  int nb = cdiv(N, CHUNK);
  k_chunksum<<<nb, B, 0, stream>>>(cnt, csum, N);
  k_scancsum<<<1, 1, 0, stream>>>(csum, nb, grptr, N, E);
  k_fillrptr<<<nb, B, 0, stream>>>(cnt, csum, grptr, N);
  k_fill<<<cdiv(E, B), B, 0, stream>>>(src, dst, dis, cnt, gsrc, gw, E);

  // ChebConv into d_out: k=0 dense (+bias), k=1..4 fused gather+recurrence+GEMM
  k_gemm32b<<<cdiv(N, 8), B, 0, stream>>>(patch, cheb_w, cheb_b, out, N);
  k_cheb2<<<cdiv(N, 4), B, 0, stream>>>(patch, nullptr, grptr, gsrc, gw,
                                        cheb_w + 1024, 1.f, R0, out, N);
  k_cheb2<<<cdiv(N, 4), B, 0, stream>>>(R0, patch, grptr, gsrc, gw,
                                        cheb_w + 2048, 2.f, R1, out, N);
  k_cheb2<<<cdiv(N, 4), B, 0, stream>>>(R1, R0, grptr, gsrc, gw,
                                        cheb_w + 3072, 2.f, R0, out, N);
  k_cheb2<<<cdiv(N, 4), B, 0, stream>>>(R0, R1, grptr, gsrc, gw,
                                        cheb_w + 4096, 2.f, nullptr, out, N);

  // SuperGAT: h = x @ lin_w (+ per-node attention scalars), then fused
  // no-max-softmax gather + epilogue + BN stats
  k_gemmh<<<cdiv(N, 4), B, 0, stream>>>(out, lin_w, att_l, att_r, h, bl, br, N);
  k_expgat2<<<cdiv(N, 4), B, 0, stream>>>(h, grptr, gsrc, bl, br, gat_b, out, bns, N);
  k_bnfinal<<<cdiv(NC, B), B, 0, stream>>>(out, bns, bn_g, bn_b, out, N);
}

// Round 4
// 1004.768 us; speedup vs baseline: 1.2642x; 1.2642x over previous
//
#include <hip/hip_runtime.h>
#include <math.h>

#define CC 32
#define CHUNK 4096  // 256 threads * 16 elems, for the rptr scan

static inline int cdiv(long long a, int b) { return (int)((a + b - 1) / b); }

// ---------- degree (by src, float) + CSR count (by dst, int) in one pass ----------
__global__ void k_degcnt(const int* __restrict__ src, const int* __restrict__ dst,
                         float* __restrict__ deg, int* __restrict__ cnt, int E) {
  int e = blockIdx.x * blockDim.x + threadIdx.x;
  if (e < E) {
    atomicAdd(&deg[src[e]], 1.0f);
    atomicAdd(&cnt[dst[e]], 1);
  }
}

__global__ void k_dis(float* __restrict__ dis, int N) {
  int i = blockIdx.x * blockDim.x + threadIdx.x;
  if (i < N) {
    float d = dis[i];
    dis[i] = (d > 0.f) ? rsqrtf(fmaxf(d, 1.f)) : 0.f;
  }
}

// ---------- CSR build: chunk sums -> serial chunk scan -> per-chunk fill ----------
__global__ void k_chunksum(const int* __restrict__ cnt, int* __restrict__ csum, int N) {
  int base = blockIdx.x * CHUNK;
  int v = 0;
  for (int i = threadIdx.x; i < CHUNK; i += 256) {
    int idx = base + i;
    if (idx < N) v += cnt[idx];
  }
  for (int m = 32; m; m >>= 1) v += __shfl_xor(v, m);
  __shared__ int ws[4];
  if ((threadIdx.x & 63) == 0) ws[threadIdx.x >> 6] = v;
  __syncthreads();
  if (threadIdx.x == 0) csum[blockIdx.x] = ws[0] + ws[1] + ws[2] + ws[3];
}

__global__ void k_scancsum(int* __restrict__ csum, int nb, int* __restrict__ rptr,
                           int N, int tot) {
  int acc = 0;
  for (int i = 0; i < nb; ++i) { int v = csum[i]; csum[i] = acc; acc += v; }
  rptr[N] = tot;
}

// exclusive scan within chunk; writes rptr[i] and cursor (in-place over cnt)
__global__ void k_fillrptr(int* __restrict__ cnt, const int* __restrict__ csum,
                           int* __restrict__ rptr, int N) {
  int base = blockIdx.x * CHUNK + threadIdx.x * 16;
  int v[16];
  int tot = 0;
#pragma unroll
  for (int q = 0; q < 16; ++q) {
    int idx = base + q;
    v[q] = (idx < N) ? cnt[idx] : 0;
    tot += v[q];
  }
  __shared__ int sh[256];
  sh[threadIdx.x] = tot;
  __syncthreads();
  for (int off = 1; off < 256; off <<= 1) {
    int add = (threadIdx.x >= off) ? sh[threadIdx.x - off] : 0;
    __syncthreads();
    sh[threadIdx.x] += add;
    __syncthreads();
  }
  int excl = sh[threadIdx.x] - tot + csum[blockIdx.x];
#pragma unroll
  for (int q = 0; q < 16; ++q) {
    int idx = base + q;
    if (idx < N) { rptr[idx] = excl; cnt[idx] = excl; }
    excl += v[q];
  }
}

// fill E real edges with w = -dis*dis (self-loops handled in-register by GAT)
__global__ void k_fill(const int* __restrict__ src, const int* __restrict__ dst,
                       const float* __restrict__ dis, int* __restrict__ cursor,
                       int* __restrict__ gsrc, float* __restrict__ gw, int E) {
  int e = blockIdx.x * blockDim.x + threadIdx.x;
  if (e >= E) return;
  int s = src[e], d = dst[e];
  int p = atomicAdd(&cursor[d], 1);
  gsrc[p] = s;
  gw[p] = -dis[s] * dis[d];
}

// ---------- fused Cheb step: gather-prop + recurrence + out += Tx@W ----------
// one 32-lane group per node; lane = channel. Load+FMA only after broadcast ->
// loads pipeline (MLP via unroll), no post-load cross-lane ops.
__global__ void k_cheb(const float* __restrict__ x_in, const float* __restrict__ x_sub,
                       const int* __restrict__ rptr, const int* __restrict__ ssrc,
                       const float* __restrict__ sw, const float* __restrict__ W,
                       float scale, float* __restrict__ tx_out, float* __restrict__ out,
                       int N) {
  __shared__ float wl[1024];
  for (int i = threadIdx.x; i < 1024; i += 256) wl[i] = W[i];
  __syncthreads();
  int node = blockIdx.x * 8 + (threadIdx.x >> 5);
  int lane = threadIdx.x & 31;
  if (node >= N) return;
  int beg = rptr[node], end = rptr[node + 1];
  float t = 0.f;
  for (int base = beg; base < end; base += 32) {
    int rem = end - base;
    int sj = 0; float wj = 0.f;
    if (lane < rem) { sj = ssrc[base + lane]; wj = sw[base + lane]; }
    int cnt = rem < 32 ? rem : 32;
#pragma unroll 8
    for (int q = 0; q < cnt; ++q) {
      int s = __shfl(sj, q, 32);
      float w = __shfl(wj, q, 32);
      t += w * x_in[(long long)s * 32 + lane];
    }
  }
  float txn = scale * t;
  if (x_sub) txn -= x_sub[(long long)node * 32 + lane];
  long long o = (long long)node * 32 + lane;
  if (tx_out) tx_out[o] = txn;
  float acc = 0.f;
#pragma unroll
  for (int q = 0; q < 32; ++q)
    acc += __shfl(txn, q, 32) * wl[q * 32 + lane];
  out[o] += acc;
}

// out[row][col] = T[row][:] @ W[32][32] + bias[col]   (k=0 term, init)
__global__ void k_gemm32b(const float* __restrict__ T, const float* __restrict__ W,
                          const float* __restrict__ bias, float* __restrict__ out,
                          int N) {
  __shared__ float w[1024];
  for (int i = threadIdx.x; i < 1024; i += 256) w[i] = W[i];
  __syncthreads();
  int row = blockIdx.x * 8 + (threadIdx.x >> 5);
  int col = threadIdx.x & 31;
  if (row >= N) return;
  const float* tr = T + (long long)row * 32;
  float acc = 0.f;
#pragma unroll
  for (int c = 0; c < 32; ++c) acc += tr[c] * w[c * 32 + col];
  out[(long long)row * 32 + col] = acc + bias[col];
}

// h2 = x @ lin_w stored HEAD-INTERLEAVED: float2 {head0[c], head1[c]} at
// h[row*32 + c]. Also per-node attention scalars bl = h.att_l, br = h.att_r
// (float2 over heads). One 64-lane wave per row; col = hd*32 + ch.
__global__ void k_gemmh(const float* __restrict__ T, const float* __restrict__ W,
                        const float* __restrict__ attl, const float* __restrict__ attr,
                        float* __restrict__ h, float* __restrict__ bl,
                        float* __restrict__ br, int N) {
  __shared__ float w[2048];
  for (int i = threadIdx.x; i < 2048; i += 256) w[i] = W[i];
  __syncthreads();
  int row = blockIdx.x * 4 + (threadIdx.x >> 6);
  int col = threadIdx.x & 63;
  if (row >= N) return;
  const float* tr = T + (long long)row * 32;
  float acc = 0.f;
#pragma unroll
  for (int c = 0; c < 32; ++c) acc += tr[c] * w[c * 64 + col];
  // interleaved store: channel (col&31), head (col>>5)
  h[(long long)row * 64 + (col & 31) * 2 + (col >> 5)] = acc;
  float pl = acc * attl[col], pr = acc * attr[col];
#pragma unroll
  for (int m = 16; m; m >>= 1) {
    pl += __shfl_xor(pl, m, 64);
    pr += __shfl_xor(pr, m, 64);
  }
  if ((col & 31) == 0) {
    bl[row * 2 + (col >> 5)] = pl;
    br[row * 2 + (col >> 5)] = pr;
  }
}

// ---------- fused SuperGAT: round-2 loop shape, bl/br precomputed, no-max
// softmax, in-register self-loop, head-interleaved float2 h, 2x unrolled body.
// One 32-lane group per node; lane = channel.
__global__ void k_expgat3(const float2* __restrict__ h2, const int* __restrict__ rptr,
                          const int* __restrict__ gsrc, const float2* __restrict__ bl,
                          const float2* __restrict__ br, const float* __restrict__ gb,
                          float* __restrict__ y, float* __restrict__ bns, int N) {
  __shared__ float ls[64];
  for (int i = threadIdx.x; i < 64; i += 256) ls[i] = 0.f;
  __syncthreads();
  int node = blockIdx.x * 8 + (threadIdx.x >> 5);
  int lane = threadIdx.x & 31;
  if (node < N) {
    float2 i2 = h2[(long long)node * 32 + lane];
    float2 brn = br[node];
    float2 bln = bl[node];
    // self-loop (j == i, linear term = bl[node] + br[node])
    float d0 = i2.x * i2.x, d1 = i2.y * i2.y;
#pragma unroll
    for (int m = 16; m; m >>= 1) {
      d0 += __shfl_xor(d0, m, 32);
      d1 += __shfl_xor(d1, m, 32);
    }
    float a0 = (bln.x + brn.x) / (1.f + __expf(-d0));
    float a1 = (bln.y + brn.y) / (1.f + __expf(-d1));
    a0 = (a0 > 0.f) ? a0 : 0.2f * a0;
    a1 = (a1 > 0.f) ? a1 : 0.2f * a1;
    float e0 = __expf(a0), e1 = __expf(a1);
    float s0 = e0, s1 = e1;
    float v0 = e0 * i2.x, v1 = e1 * i2.y;
    int beg = rptr[node], end = rptr[node + 1];
    for (int base = beg; base < end; base += 32) {
      int rem = end - base;
      int sj = 0; float bx = 0.f, by = 0.f;
      if (lane < rem) {
        sj = gsrc[base + lane];
        float2 b2 = bl[sj];
        bx = b2.x; by = b2.y;
      }
      int cnt = rem < 32 ? rem : 32;
      int q = 0;
      // 2-way interleaved: two independent loads + four butterfly chains in flight
      for (; q + 2 <= cnt; q += 2) {
        int sA = __shfl(sj, q, 32);
        int sB = __shfl(sj, q + 1, 32);
        float2 jA = h2[(long long)sA * 32 + lane];
        float2 jB = h2[(long long)sB * 32 + lane];
        float gA0 = jA.x * i2.x, gA1 = jA.y * i2.y;
        float gB0 = jB.x * i2.x, gB1 = jB.y * i2.y;
#pragma unroll
        for (int m = 16; m; m >>= 1) {
          gA0 += __shfl_xor(gA0, m, 32);
          gA1 += __shfl_xor(gA1, m, 32);
          gB0 += __shfl_xor(gB0, m, 32);
          gB1 += __shfl_xor(gB1, m, 32);
        }
        float lA0 = __shfl(bx, q, 32) + brn.x;
        float lA1 = __shfl(by, q, 32) + brn.y;
        float lB0 = __shfl(bx, q + 1, 32) + brn.x;
        float lB1 = __shfl(by, q + 1, 32) + brn.y;
        float aA0 = lA0 / (1.f + __expf(-gA0));
        float aA1 = lA1 / (1.f + __expf(-gA1));
        float aB0 = lB0 / (1.f + __expf(-gB0));
        float aB1 = lB1 / (1.f + __expf(-gB1));
        aA0 = (aA0 > 0.f) ? aA0 : 0.2f * aA0;
        aA1 = (aA1 > 0.f) ? aA1 : 0.2f * aA1;
        aB0 = (aB0 > 0.f) ? aB0 : 0.2f * aB0;
        aB1 = (aB1 > 0.f) ? aB1 : 0.2f * aB1;
        float eA0 = __expf(aA0), eA1 = __expf(aA1);
        float eB0 = __expf(aB0), eB1 = __expf(aB1);
        s0 += eA0 + eB0; s1 += eA1 + eB1;
        v0 += eA0 * jA.x + eB0 * jB.x;
        v1 += eA1 * jA.y + eB1 * jB.y;
      }
      if (q < cnt) {
        int sA = __shfl(sj, q, 32);
        float2 jA = h2[(long long)sA * 32 + lane];
        float gA0 = jA.x * i2.x, gA1 = jA.y * i2.y;
#pragma unroll
        for (int m = 16; m; m >>= 1) {
          gA0 += __shfl_xor(gA0, m, 32);
          gA1 += __shfl_xor(gA1, m, 32);
        }
        float lA0 = __shfl(bx, q, 32) + brn.x;
        float lA1 = __shfl(by, q, 32) + brn.y;
        float aA0 = lA0 / (1.f + __expf(-gA0));
        float aA1 = lA1 / (1.f + __expf(-gA1));
        aA0 = (aA0 > 0.f) ? aA0 : 0.2f * aA0;
        aA1 = (aA1 > 0.f) ? aA1 : 0.2f * aA1;
        float eA0 = __expf(aA0), eA1 = __expf(aA1);
        s0 += eA0; s1 += eA1;
        v0 += eA0 * jA.x;
        v1 += eA1 * jA.y;
      }
    }
    float x2 = 0.5f * (v0 / s0 + v1 / s1) + gb[lane];
    float yv = ((x2 > 0.f) ? x2 : 0.01f * x2) + x2;  // leaky 0.01 + residual
    y[(long long)node * 32 + lane] = yv;
    atomicAdd(&ls[lane], yv);
    atomicAdd(&ls[32 + lane], yv * yv);
  }
  __syncthreads();
  if (threadIdx.x < 64) atomicAdd(&bns[threadIdx.x], ls[threadIdx.x]);
}

// in-place safe (y may alias out)
__global__ void k_bnfinal(const float* __restrict__ y, const float* __restrict__ bns,
                          const float* __restrict__ g, const float* __restrict__ b,
                          float* __restrict__ out, int N) {
  int i = blockIdx.x * blockDim.x + threadIdx.x;
  if (i >= N * CC) return;
  int c = i & 31;
  float inv_n = 1.f / (float)N;
  float mu = bns[c] * inv_n;
  float var = bns[32 + c] * inv_n - mu * mu;
  out[i] = (y[i] - mu) * rsqrtf(var + 1e-5f) * g[c] + b[c];
}

extern "C" void kernel_launch(void* const* d_in, const int* in_sizes, int n_in,
                              void* d_out, int out_size, void* d_ws, size_t ws_size,
                              hipStream_t stream) {
  const float* patch = (const float*)d_in[0];
  const int* eidx = (const int*)d_in[1];
  // d_in[2] = edge_attr (unused by reference)
  const float* cheb_w = (const float*)d_in[3];
  const float* cheb_b = (const float*)d_in[4];
  const float* lin_w = (const float*)d_in[5];
  const float* att_l = (const float*)d_in[6];
  const float* att_r = (const float*)d_in[7];
  const float* gat_b = (const float*)d_in[8];
  const float* bn_g = (const float*)d_in[9];
  const float* bn_b = (const float*)d_in[10];
  float* out = (float*)d_out;

  const int N = in_sizes[0] / CC;   // 100000
  const int E = in_sizes[1] / 2;    // 1600000
  const int* src = eidx;
  const int* dst = eidx + E;

  // workspace layout (~40 MB); all region starts even-float (8B) aligned
  float* R0 = (float*)d_ws;                  // N*32 (Tx ping; h = R0..R1 as N*64)
  float* R1 = R0 + (size_t)N * 32;           // N*32 (Tx pong)
  float* gw = R1 + (size_t)N * 32;           // E floats (cheb edge weights)
  int* gsrc = (int*)(gw + E);                // E ints (dst-sorted src)
  int* grptr = gsrc + E;                     // N+2 ints (CSR row ptr, padded even)
  int* cnt = grptr + (N + 2);                // N ints (count, then cursor) [zeroed]
  int* csum = cnt + N;                       // 64 ints (chunk sums)       [zeroed]
  float* dis = (float*)(csum + 64);          // N floats                   [zeroed]
  float* bns = dis + N;                      // 64 floats                  [zeroed]
  float* bl = bns + 64;                      // N*2 floats (h . att_l per head)
  float* br = bl + (size_t)N * 2;            // N*2 floats (h . att_r per head)
  float* h = R0;                             // N*64 overlays R0..R1 after cheb

  const int B = 256;
  const long long NC = (long long)N * 32;

  // zero cnt, csum, dis, bns in one shot (contiguous)
  hipMemsetAsync(cnt, 0, sizeof(int) * ((size_t)N * 2 + 128), stream);

  // degree-by-src (sym norm) + count-by-dst (CSR) in one pass
  k_degcnt<<<cdiv(E, B), B, 0, stream>>>(src, dst, dis, cnt, E);
  k_dis<<<cdiv(N, B), B, 0, stream>>>(dis, N);

  // CSR build over E real edges (self-loops handled in-register by GAT)
  int nb = cdiv(N, CHUNK);
  k_chunksum<<<nb, B, 0, stream>>>(cnt, csum, N);
  k_scancsum<<<1, 1, 0, stream>>>(csum, nb, grptr, N, E);
  k_fillrptr<<<nb, B, 0, stream>>>(cnt, csum, grptr, N);
  k_fill<<<cdiv(E, B), B, 0, stream>>>(src, dst, dis, cnt, gsrc, gw, E);

  // ChebConv into d_out: k=0 dense (+bias), k=1..4 fused gather+recurrence+GEMM
  k_gemm32b<<<cdiv(N, 8), B, 0, stream>>>(patch, cheb_w, cheb_b, out, N);
  k_cheb<<<cdiv(N, 8), B, 0, stream>>>(patch, nullptr, grptr, gsrc, gw,
                                       cheb_w + 1024, 1.f, R0, out, N);
  k_cheb<<<cdiv(N, 8), B, 0, stream>>>(R0, patch, grptr, gsrc, gw,
                                       cheb_w + 2048, 2.f, R1, out, N);
  k_cheb<<<cdiv(N, 8), B, 0, stream>>>(R1, R0, grptr, gsrc, gw,
                                       cheb_w + 3072, 2.f, R0, out, N);
  k_cheb<<<cdiv(N, 8), B, 0, stream>>>(R0, R1, grptr, gsrc, gw,
                                       cheb_w + 4096, 2.f, nullptr, out, N);

  // SuperGAT: h2 = x @ lin_w (interleaved) + per-node attention scalars,
  // then fused no-max-softmax gather + epilogue + BN stats
  k_gemmh<<<cdiv(N, 4), B, 0, stream>>>(out, lin_w, att_l, att_r, h, bl, br, N);
  k_expgat3<<<cdiv(N, 8), B, 0, stream>>>((const float2*)h, grptr, gsrc,
                                          (const float2*)bl, (const float2*)br,
                                          gat_b, out, bns, N);
  k_bnfinal<<<cdiv(NC, B), B, 0, stream>>>(out, bns, bn_g, bn_b, out, N);
}